// Round 6
// baseline (434.440 us; speedup 1.0000x reference)
//
#include <hip/hip_runtime.h>
#include <hip/hip_fp16.h>

#define D 128
#define NB_MAX 1024
#define PART_BLOCKS 256

using f32x4  = __attribute__((ext_vector_type(4))) float;
using half8  = __attribute__((ext_vector_type(8))) _Float16;
using short8 = __attribute__((ext_vector_type(8))) short;

#define AS1(p) ((const __attribute__((address_space(1))) void*)(p))
#define AS3(p) ((__attribute__((address_space(3))) void*)(p))

// ------------------------------------------------ fused prep:
//  blocks [0,xb)            : x fp32 -> fp16
//  blocks [xb, xb+512)      : W1/W2 -> f16 hi/lo planes (k-major swizzle)
//  blocks [xb+512, ...)     : zero bucket_counts
// Wg layout: (((kc*2 + plane)*4 + q)*128 + col)*8 + j ; k = kc*32+q*8+j
__global__ void prep_k(const float* __restrict__ x, __half* __restrict__ y, int n4,
                       const float* __restrict__ W1s, const float* __restrict__ W1n,
                       const float* __restrict__ W2s, const float* __restrict__ W2n,
                       unsigned short* __restrict__ Wg1, unsigned short* __restrict__ Wg2,
                       int* __restrict__ bucket_counts, int nb, int xb) {
    int b = blockIdx.x;
    int t = threadIdx.x;
    if (b < xb) {
        int i = b * 256 + t;
        if (i < n4) {
            float4 v = *(const float4*)(x + (size_t)i * 4);
            __half2 h0 = __floats2half2_rn(v.x, v.y);
            __half2 h1 = __floats2half2_rn(v.z, v.w);
            __half2* o = (__half2*)(y + (size_t)i * 4);
            o[0] = h0; o[1] = h1;
        }
        return;
    }
    int wb = b - xb;
    if (wb < 512) {
        int sel = wb >> 8;              // 0: W1, 1: W2
        int lb  = wb & 255;
        if (lb >= 128) return;
        const float* Ws = sel ? W2s : W1s;
        const float* Wn = sel ? W2n : W1n;
        unsigned short* Wg = sel ? Wg2 : Wg1;
        int idx = lb * 256 + t;          // 0 .. 32767
        int col = idx >> 8;
        int k   = idx & 255;
        float v = (k < 128) ? Ws[k * D + col] : Wn[(k - 128) * D + col];
        _Float16 hv = (_Float16)v;
        _Float16 lv = (_Float16)(v - (float)hv);
        int kc = k >> 5, q = (k >> 3) & 3, j = k & 7;
        Wg[(((kc * 2 + 0) * 4 + q) * 128 + col) * 8 + j] = *(unsigned short*)&hv;
        Wg[(((kc * 2 + 1) * 4 + q) * 128 + col) * 8 + j] = *(unsigned short*)&lv;
        return;
    }
    int i = (wb - 512) * 256 + t;
    if (i < nb) bucket_counts[i] = 0;
}

// ------------------------------------------------ CSR build, bucketed (256 nodes/bucket)
__global__ void bucket_count_k(const int* __restrict__ dst, int* __restrict__ bucket_counts,
                               int E, int nb) {
    __shared__ int hist[NB_MAX];
    int t = threadIdx.x;
    for (int b = t; b < nb; b += 256) hist[b] = 0;
    __syncthreads();
    for (int i = blockIdx.x * 256 + t; i < E; i += gridDim.x * 256)
        atomicAdd(&hist[dst[i] >> 8], 1);
    __syncthreads();
    for (int b = t; b < nb; b += 256) {
        int c = hist[b];
        if (c) atomicAdd(&bucket_counts[b], c);
    }
}

__global__ void bucket_scan_k(const int* __restrict__ bucket_counts,
                              int* __restrict__ bucket_base,
                              int* __restrict__ bucket_cursor, int nb) {
    __shared__ int sh[256];
    int t = threadIdx.x;
    int base = t * 4;
    int v0 = (base + 0 < nb) ? bucket_counts[base + 0] : 0;
    int v1 = (base + 1 < nb) ? bucket_counts[base + 1] : 0;
    int v2 = (base + 2 < nb) ? bucket_counts[base + 2] : 0;
    int v3 = (base + 3 < nb) ? bucket_counts[base + 3] : 0;
    int tsum = v0 + v1 + v2 + v3;
    sh[t] = tsum;
    __syncthreads();
    for (int off = 1; off < 256; off <<= 1) {
        int x = 0;
        if (t >= off) x = sh[t - off];
        __syncthreads();
        if (t >= off) sh[t] += x;
        __syncthreads();
    }
    int excl = sh[t] - tsum;
    if (base + 0 < nb) { bucket_base[base+0] = excl;          bucket_cursor[base+0] = excl; }
    if (base + 1 < nb) { bucket_base[base+1] = excl+v0;       bucket_cursor[base+1] = excl+v0; }
    if (base + 2 < nb) { bucket_base[base+2] = excl+v0+v1;    bucket_cursor[base+2] = excl+v0+v1; }
    if (base + 3 < nb) { bucket_base[base+3] = excl+v0+v1+v2; bucket_cursor[base+3] = excl+v0+v1+v2; }
    if (t == 255) bucket_base[nb] = sh[255];
}

__global__ void partition_k(const int* __restrict__ src, const int* __restrict__ dst,
                            int* __restrict__ bucket_cursor, unsigned* __restrict__ pairs,
                            int E, int nb, int chunk) {
    __shared__ int hist[NB_MAX];
    __shared__ int bbase[NB_MAX];
    int t = threadIdx.x;
    int e0 = blockIdx.x * chunk;
    int e1 = min(E, e0 + chunk);
    for (int b = t; b < nb; b += 256) hist[b] = 0;
    __syncthreads();
    for (int i = e0 + t; i < e1; i += 256)
        atomicAdd(&hist[dst[i] >> 8], 1);
    __syncthreads();
    for (int b = t; b < nb; b += 256) {
        int c = hist[b];
        int bs = 0;
        if (c) bs = atomicAdd(&bucket_cursor[b], c);
        bbase[b] = bs;
        hist[b] = 0;            // reuse as local cursor
    }
    __syncthreads();
    for (int i = e0 + t; i < e1; i += 256) {
        int dd = dst[i];
        int b = dd >> 8;
        int r = atomicAdd(&hist[b], 1);
        pairs[bbase[b] + r] = ((unsigned)(dd & 255) << 17) | (unsigned)src[i];
    }
}

__global__ void build_csr_k(const unsigned* __restrict__ pairs,
                            const int* __restrict__ bucket_base,
                            int* __restrict__ counts, int* __restrict__ offsets,
                            int* __restrict__ edge_src, int N) {
    __shared__ int hist[256];
    __shared__ int curs[256];
    __shared__ int sh[256];
    int t = threadIdx.x;
    int b = blockIdx.x;
    int n0 = b << 8;
    int e0 = bucket_base[b];
    int e1 = bucket_base[b + 1];
    hist[t] = 0;
    __syncthreads();
    for (int i = e0 + t; i < e1; i += 256)
        atomicAdd(&hist[pairs[i] >> 17], 1);
    __syncthreads();
    int c = hist[t];
    sh[t] = c;
    __syncthreads();
    for (int off = 1; off < 256; off <<= 1) {
        int x = 0;
        if (t >= off) x = sh[t - off];
        __syncthreads();
        if (t >= off) sh[t] += x;
        __syncthreads();
    }
    int excl = sh[t] - c;
    curs[t] = excl;
    int node = n0 + t;
    if (node < N) { counts[node] = c; offsets[node] = e0 + excl; }
    __syncthreads();
    for (int i = e0 + t; i < e1; i += 256) {
        unsigned p = pairs[i];
        int pos = atomicAdd(&curs[p >> 17], 1);
        edge_src[e0 + pos] = (int)(p & 0x1FFFFu);
    }
}

// ------------------------------------------------ neighbor mean, fp16 in/out
// 4 nodes per wave: 16-lane slot owns one node's full 128-feat row (8 halves
// per lane). 8 independent row loads in flight per lane; no cross-lane reduce.
__global__ void aggregate_f16_k(const __half* __restrict__ x,
                                const int* __restrict__ edge_src,
                                const int* __restrict__ offsets,
                                const int* __restrict__ counts,
                                __half* __restrict__ agg, int n, int E1) {
    int gwave = (blockIdx.x * blockDim.x + threadIdx.x) >> 6;
    int lane  = threadIdx.x & 63;
    int slot  = lane >> 4;          // 0..3: node slot
    int sub   = lane & 15;          // feature group (8 halves)
    int node  = gwave * 4 + slot;
    bool act  = node < n;
    int start = act ? offsets[node] : 0;
    int cnt   = act ? counts[node] : 0;
    int mc = cnt;
    mc = max(mc, __shfl(mc, lane ^ 16));
    mc = max(mc, __shfl(mc, lane ^ 32));
    float acc[8] = {0.f, 0.f, 0.f, 0.f, 0.f, 0.f, 0.f, 0.f};
    for (int base = 0; base < mc; base += 16) {
        int ids = edge_src[min(start + base + sub, E1)];
        #pragma unroll
        for (int h = 0; h < 2; ++h) {
            float4 raw[8];
            float  wg[8];
            #pragma unroll
            for (int r = 0; r < 8; ++r) {
                int e = base + h * 8 + r;
                int row = __shfl(ids, (lane & 48) | (h * 8 + r));
                wg[r] = (e < cnt) ? 1.0f : 0.0f;
                raw[r] = *(const float4*)(x + (size_t)row * D + sub * 8);
            }
            #pragma unroll
            for (int r = 0; r < 8; ++r) {
                union { float4 f4; half8 h8; } cv;
                cv.f4 = raw[r];
                #pragma unroll
                for (int j = 0; j < 8; ++j)
                    acc[j] = fmaf((float)cv.h8[j], wg[r], acc[j]);
            }
        }
    }
    if (act) {
        float inv = 1.0f / fmaxf((float)cnt, 1.0f);
        union { __half2 h2[4]; short8 s8; } u;
        #pragma unroll
        for (int j = 0; j < 4; ++j)
            u.h2[j] = __floats2half2_rn(acc[2 * j] * inv, acc[2 * j + 1] * inv);
        *(short8*)(agg + (size_t)node * D + sub * 8) = u.s8;
    }
}

// ------------------------------------------------ fp16 2-term MFMA GEMM
// C = A0 @ W[:128] + A1 @ W[128:] + b, W = Whi + Wlo (f16 split).
// Double-buffered 16KB B staging: stage(kc+1)+A(kc+1) issued AFTER the
// barrier so the vmcnt(0) drain at the NEXT barrier finds them complete.
// One barrier per kc; stage/A latency hidden behind 32 MFMAs.
__global__ __launch_bounds__(256)
void mfma_gemm_k(const _Float16* __restrict__ A0, const _Float16* __restrict__ A1,
                 const unsigned short* __restrict__ Wg,
                 const float* __restrict__ bias,
                 float* __restrict__ C, __half* __restrict__ Ch,
                 int n, int out_mode) {
    __shared__ __align__(16) unsigned short lds_b[2][8192];   // 2 x 16 KB
    int t = threadIdx.x;
    int w = t >> 6;
    int l = t & 63;
    int m = l & 15;          // A row within tile / B,C col within tile
    int q = l >> 4;          // quad
    int r0 = blockIdx.x * 128 + w * 32;

    f32x4 acc[2][8];
    #pragma unroll
    for (int rt = 0; rt < 2; ++rt)
        #pragma unroll
        for (int ct = 0; ct < 8; ++ct)
            acc[rt][ct] = (f32x4){0.f, 0.f, 0.f, 0.f};

    // prologue: stage kc=0, prefetch A(0)
    #pragma unroll
    for (int i = 0; i < 4; ++i) {
        int e = i * 256 + t;
        __builtin_amdgcn_global_load_lds(AS1(Wg + e * 8), AS3(&lds_b[0][e * 8]), 16, 0, 0);
    }
    half8 a_cur[2], a_nxt[2];
    a_nxt[0] = a_nxt[1] = (half8){0, 0, 0, 0, 0, 0, 0, 0};
    #pragma unroll
    for (int rt = 0; rt < 2; ++rt) {
        int row = r0 + rt * 16 + m;
        half8 v = (half8){0, 0, 0, 0, 0, 0, 0, 0};
        if (row < n) v = *(const half8*)(A0 + (size_t)row * D + q * 8);
        a_cur[rt] = v;
    }

    for (int kc = 0; kc < 8; ++kc) {
        int p = kc & 1;
        __syncthreads();          // drains stage(kc) + A(kc) loads
        if (kc < 7) {
            const unsigned short* gk = Wg + (size_t)(kc + 1) * 8192;
            #pragma unroll
            for (int i = 0; i < 4; ++i) {
                int e = i * 256 + t;
                __builtin_amdgcn_global_load_lds(AS1(gk + e * 8), AS3(&lds_b[1 - p][e * 8]), 16, 0, 0);
            }
            const _Float16* __restrict__ An = ((kc + 1) < 4) ? A0 : A1;
            int kan = ((kc + 1) & 3) * 32;
            #pragma unroll
            for (int rt = 0; rt < 2; ++rt) {
                int row = r0 + rt * 16 + m;
                half8 v = (half8){0, 0, 0, 0, 0, 0, 0, 0};
                if (row < n) v = *(const half8*)(An + (size_t)row * D + kan + q * 8);
                a_nxt[rt] = v;
            }
        }
        #pragma unroll
        for (int ct = 0; ct < 8; ++ct) {
            half8 bh = *(const half8*)&lds_b[p][(size_t)(q * 128 + ct * 16 + m) * 8];
            half8 bl = *(const half8*)&lds_b[p][(size_t)((4 + q) * 128 + ct * 16 + m) * 8];
            #pragma unroll
            for (int rt = 0; rt < 2; ++rt) {
                acc[rt][ct] = __builtin_amdgcn_mfma_f32_16x16x32_f16(a_cur[rt], bh, acc[rt][ct], 0, 0, 0);
                acc[rt][ct] = __builtin_amdgcn_mfma_f32_16x16x32_f16(a_cur[rt], bl, acc[rt][ct], 0, 0, 0);
            }
        }
        a_cur[0] = a_nxt[0];
        a_cur[1] = a_nxt[1];
    }

    #pragma unroll
    for (int ct = 0; ct < 8; ++ct) {
        int col = ct * 16 + m;
        float bb = bias[col];
        #pragma unroll
        for (int rt = 0; rt < 2; ++rt) {
            #pragma unroll
            for (int r = 0; r < 4; ++r) {
                int row = r0 + rt * 16 + q * 4 + r;
                if (row < n) {
                    float v = acc[rt][ct][r] + bb;
                    if (out_mode) {
                        v = fmaxf(v, 0.f);
                        Ch[(size_t)row * D + col] = __float2half(v);
                    } else {
                        C[(size_t)row * D + col] = v;
                    }
                }
            }
        }
    }
}

// ------------------------------------------------------------------- launch
extern "C" void kernel_launch(void* const* d_in, const int* in_sizes, int n_in,
                              void* d_out, int out_size, void* d_ws, size_t ws_size,
                              hipStream_t stream) {
    const float* in_feat = (const float*)d_in[0];
    const float* W1s     = (const float*)d_in[1];
    const float* W1n     = (const float*)d_in[2];
    const float* b1      = (const float*)d_in[3];
    const float* W2s     = (const float*)d_in[4];
    const float* W2n     = (const float*)d_in[5];
    const float* b2      = (const float*)d_in[6];
    const int*   src     = (const int*)d_in[7];
    const int*   dst     = (const int*)d_in[8];

    const int N  = in_sizes[0] / D;
    const int E  = in_sizes[7];
    const int NB = (N + 255) >> 8;     // 256-node buckets

    // workspace layout
    char* base = (char*)d_ws;
    size_t off = 0;
    __half* agg16 = (__half*)(base + off); off += (size_t)N * D * 2;   // neighbor means
    __half* xh16  = (__half*)(base + off); off += (size_t)N * D * 2;   // x16, then h16 (in-place)
    int* edge_src = (int*)(base + off);    off += (size_t)E * 4;
    int* counts   = (int*)(base + off);    off += (size_t)N * 4;
    int* offsets  = (int*)(base + off);    off += (size_t)N * 4;
    unsigned short* Wg1 = (unsigned short*)(base + off); off += 65536 * 2;
    unsigned short* Wg2 = (unsigned short*)(base + off); off += 65536 * 2;
    int* bucket_counts = (int*)(base + off); off += NB_MAX * 4;
    int* bucket_base   = (int*)(base + off); off += (NB_MAX + 1) * 4;
    off = (off + 15) & ~(size_t)15;
    int* bucket_cursor = (int*)(base + off); off += NB_MAX * 4;

    unsigned* pairs = (unsigned*)agg16;  // aliases agg16 (consumed before agg16 written)

    const int chunk = (E + PART_BLOCKS - 1) / PART_BLOCKS;
    const int n4 = (N * D) / 4;
    const int xb = (n4 + 255) / 256;
    const int zb = (NB + 255) / 256;

    // fused prep: x->fp16, W1/W2 hi-lo split, zero bucket counts
    hipLaunchKernelGGL(prep_k, dim3(xb + 512 + zb), dim3(256), 0, stream,
                       in_feat, xh16, n4, W1s, W1n, W2s, W2n, Wg1, Wg2,
                       bucket_counts, NB, xb);

    // CSR build (bucketed counting sort by dst)
    hipLaunchKernelGGL(bucket_count_k, dim3(PART_BLOCKS), dim3(256), 0, stream,
                       dst, bucket_counts, E, NB);
    hipLaunchKernelGGL(bucket_scan_k, dim3(1), dim3(256), 0, stream,
                       bucket_counts, bucket_base, bucket_cursor, NB);
    hipLaunchKernelGGL(partition_k, dim3(PART_BLOCKS), dim3(256), 0, stream,
                       src, dst, bucket_cursor, pairs, E, NB, chunk);
    hipLaunchKernelGGL(build_csr_k, dim3(NB), dim3(256), 0, stream,
                       pairs, bucket_base, counts, offsets, edge_src, N);

    const int nwaves = (N + 3) / 4;
    const dim3 aggGrid(((size_t)nwaves * 64 + 255) / 256);
    const dim3 gemmGrid((N + 127) / 128);

    // layer 1: agg(x16) -> gemm -> h16 (in-place into xh16)
    hipLaunchKernelGGL(aggregate_f16_k, aggGrid, dim3(256), 0, stream,
                       xh16, edge_src, offsets, counts, agg16, N, E - 1);
    hipLaunchKernelGGL(mfma_gemm_k, gemmGrid, dim3(256), 0, stream,
                       (const _Float16*)xh16, (const _Float16*)agg16, Wg1, b1,
                       (float*)nullptr, xh16, N, 1);

    // layer 2: agg(h16) -> gemm -> d_out fp32
    hipLaunchKernelGGL(aggregate_f16_k, aggGrid, dim3(256), 0, stream,
                       xh16, edge_src, offsets, counts, agg16, N, E - 1);
    hipLaunchKernelGGL(mfma_gemm_k, gemmGrid, dim3(256), 0, stream,
                       (const _Float16*)xh16, (const _Float16*)agg16, Wg2, b2,
                       (float*)d_out, (__half*)nullptr, N, 0);
}

// Round 7
// 355.052 us; speedup vs baseline: 1.2236x; 1.2236x over previous
//
#include <hip/hip_runtime.h>
#include <hip/hip_fp16.h>

#define D 128
#define NB_MAX 1024
#define PART_BLOCKS 512

using f32x4  = __attribute__((ext_vector_type(4))) float;
using half8  = __attribute__((ext_vector_type(8))) _Float16;
using short8 = __attribute__((ext_vector_type(8))) short;

#define AS1(p) ((const __attribute__((address_space(1))) void*)(p))
#define AS3(p) ((__attribute__((address_space(3))) void*)(p))

// ------------------------------------------------ fused prep:
//  blocks [0,xb)            : x fp32 -> fp16
//  blocks [xb, xb+512)      : W1/W2 -> f16 hi/lo planes (k-major swizzle)
//  blocks [xb+512, ...)     : zero bucket_counts
// Wg layout: (((kc*2 + plane)*4 + q)*128 + col)*8 + j ; k = kc*32+q*8+j
__global__ void prep_k(const float* __restrict__ x, __half* __restrict__ y, int n4,
                       const float* __restrict__ W1s, const float* __restrict__ W1n,
                       const float* __restrict__ W2s, const float* __restrict__ W2n,
                       unsigned short* __restrict__ Wg1, unsigned short* __restrict__ Wg2,
                       int* __restrict__ bucket_counts, int nb, int xb) {
    int b = blockIdx.x;
    int t = threadIdx.x;
    if (b < xb) {
        int i = b * 256 + t;
        if (i < n4) {
            float4 v = *(const float4*)(x + (size_t)i * 4);
            __half2 h0 = __floats2half2_rn(v.x, v.y);
            __half2 h1 = __floats2half2_rn(v.z, v.w);
            __half2* o = (__half2*)(y + (size_t)i * 4);
            o[0] = h0; o[1] = h1;
        }
        return;
    }
    int wb = b - xb;
    if (wb < 512) {
        int sel = wb >> 8;              // 0: W1, 1: W2
        int lb  = wb & 255;
        if (lb >= 128) return;
        const float* Ws = sel ? W2s : W1s;
        const float* Wn = sel ? W2n : W1n;
        unsigned short* Wg = sel ? Wg2 : Wg1;
        int idx = lb * 256 + t;          // 0 .. 32767
        int col = idx >> 8;
        int k   = idx & 255;
        float v = (k < 128) ? Ws[k * D + col] : Wn[(k - 128) * D + col];
        _Float16 hv = (_Float16)v;
        _Float16 lv = (_Float16)(v - (float)hv);
        int kc = k >> 5, q = (k >> 3) & 3, j = k & 7;
        Wg[(((kc * 2 + 0) * 4 + q) * 128 + col) * 8 + j] = *(unsigned short*)&hv;
        Wg[(((kc * 2 + 1) * 4 + q) * 128 + col) * 8 + j] = *(unsigned short*)&lv;
        return;
    }
    int i = (wb - 512) * 256 + t;
    if (i < nb) bucket_counts[i] = 0;
}

// ------------------------------------------------ CSR build, bucketed (256 nodes/bucket)
__global__ void bucket_count_k(const int* __restrict__ dst, int* __restrict__ bucket_counts,
                               int E, int nb) {
    __shared__ int hist[NB_MAX];
    int t = threadIdx.x;
    for (int b = t; b < nb; b += 256) hist[b] = 0;
    __syncthreads();
    for (int i = blockIdx.x * 256 + t; i < E; i += gridDim.x * 256)
        atomicAdd(&hist[dst[i] >> 8], 1);
    __syncthreads();
    for (int b = t; b < nb; b += 256) {
        int c = hist[b];
        if (c) atomicAdd(&bucket_counts[b], c);
    }
}

__global__ void bucket_scan_k(const int* __restrict__ bucket_counts,
                              int* __restrict__ bucket_base,
                              int* __restrict__ bucket_cursor, int nb) {
    __shared__ int sh[256];
    int t = threadIdx.x;
    int base = t * 4;
    int v0 = (base + 0 < nb) ? bucket_counts[base + 0] : 0;
    int v1 = (base + 1 < nb) ? bucket_counts[base + 1] : 0;
    int v2 = (base + 2 < nb) ? bucket_counts[base + 2] : 0;
    int v3 = (base + 3 < nb) ? bucket_counts[base + 3] : 0;
    int tsum = v0 + v1 + v2 + v3;
    sh[t] = tsum;
    __syncthreads();
    for (int off = 1; off < 256; off <<= 1) {
        int x = 0;
        if (t >= off) x = sh[t - off];
        __syncthreads();
        if (t >= off) sh[t] += x;
        __syncthreads();
    }
    int excl = sh[t] - tsum;
    if (base + 0 < nb) { bucket_base[base+0] = excl;          bucket_cursor[base+0] = excl; }
    if (base + 1 < nb) { bucket_base[base+1] = excl+v0;       bucket_cursor[base+1] = excl+v0; }
    if (base + 2 < nb) { bucket_base[base+2] = excl+v0+v1;    bucket_cursor[base+2] = excl+v0+v1; }
    if (base + 3 < nb) { bucket_base[base+3] = excl+v0+v1+v2; bucket_cursor[base+3] = excl+v0+v1+v2; }
    if (t == 255) bucket_base[nb] = sh[255];
}

__global__ void partition_k(const int* __restrict__ src, const int* __restrict__ dst,
                            int* __restrict__ bucket_cursor, unsigned* __restrict__ pairs,
                            int E, int nb, int chunk) {
    __shared__ int hist[NB_MAX];
    __shared__ int bbase[NB_MAX];
    int t = threadIdx.x;
    int e0 = blockIdx.x * chunk;
    int e1 = min(E, e0 + chunk);
    for (int b = t; b < nb; b += 256) hist[b] = 0;
    __syncthreads();
    for (int i = e0 + t; i < e1; i += 256)
        atomicAdd(&hist[dst[i] >> 8], 1);
    __syncthreads();
    for (int b = t; b < nb; b += 256) {
        int c = hist[b];
        int bs = 0;
        if (c) bs = atomicAdd(&bucket_cursor[b], c);
        bbase[b] = bs;
        hist[b] = 0;            // reuse as local cursor
    }
    __syncthreads();
    for (int i = e0 + t; i < e1; i += 256) {
        int dd = dst[i];
        int b = dd >> 8;
        int r = atomicAdd(&hist[b], 1);
        pairs[bbase[b] + r] = ((unsigned)(dd & 255) << 17) | (unsigned)src[i];
    }
}

__global__ void build_csr_k(const unsigned* __restrict__ pairs,
                            const int* __restrict__ bucket_base,
                            int* __restrict__ counts, int* __restrict__ offsets,
                            int* __restrict__ edge_src, int N) {
    __shared__ int hist[256];
    __shared__ int curs[256];
    __shared__ int sh[256];
    int t = threadIdx.x;
    int b = blockIdx.x;
    int n0 = b << 8;
    int e0 = bucket_base[b];
    int e1 = bucket_base[b + 1];
    hist[t] = 0;
    __syncthreads();
    for (int i = e0 + t; i < e1; i += 256)
        atomicAdd(&hist[pairs[i] >> 17], 1);
    __syncthreads();
    int c = hist[t];
    sh[t] = c;
    __syncthreads();
    for (int off = 1; off < 256; off <<= 1) {
        int x = 0;
        if (t >= off) x = sh[t - off];
        __syncthreads();
        if (t >= off) sh[t] += x;
        __syncthreads();
    }
    int excl = sh[t] - c;
    curs[t] = excl;
    int node = n0 + t;
    if (node < N) { counts[node] = c; offsets[node] = e0 + excl; }
    __syncthreads();
    for (int i = e0 + t; i < e1; i += 256) {
        unsigned p = pairs[i];
        int pos = atomicAdd(&curs[p >> 17], 1);
        edge_src[e0 + pos] = (int)(p & 0x1FFFFu);
    }
}

// ------------------------------------------------ neighbor mean, fp16 in/out
// 4 nodes per wave: 16-lane slot owns one node's full 128-feat row (8 halves
// per lane); 8 row loads in flight per lane; no cross-lane feature reduce.
// Padding slots (e >= cnt) are clamped to ROW 0 -> single L1-hot line, no
// HBM waste (R6's bug: random-row padding loads cost 115 MB of fetch).
__global__ void aggregate_f16_k(const __half* __restrict__ x,
                                const int* __restrict__ edge_src,
                                const int* __restrict__ offsets,
                                const int* __restrict__ counts,
                                __half* __restrict__ agg, int n) {
    int gwave = (blockIdx.x * blockDim.x + threadIdx.x) >> 6;
    int lane  = threadIdx.x & 63;
    int slot  = lane >> 4;          // 0..3: node slot
    int sub   = lane & 15;          // feature group (8 halves)
    int node  = gwave * 4 + slot;
    bool act  = node < n;
    int start = act ? offsets[node] : 0;
    int cnt   = act ? counts[node] : 0;
    int mc = cnt;
    mc = max(mc, __shfl(mc, lane ^ 16));
    mc = max(mc, __shfl(mc, lane ^ 32));
    float acc[8] = {0.f, 0.f, 0.f, 0.f, 0.f, 0.f, 0.f, 0.f};
    for (int base = 0; base < mc; base += 16) {
        int e   = base + sub;
        int ids = (e < cnt) ? edge_src[start + e] : 0;   // invalid -> row 0 (L1-hot)
        #pragma unroll
        for (int h = 0; h < 2; ++h) {
            float4 raw[8];
            float  wg[8];
            #pragma unroll
            for (int r = 0; r < 8; ++r) {
                int ei  = base + h * 8 + r;
                int row = __shfl(ids, (lane & 48) | (h * 8 + r));
                wg[r]  = (ei < cnt) ? 1.0f : 0.0f;
                raw[r] = *(const float4*)(x + (size_t)row * D + sub * 8);
            }
            #pragma unroll
            for (int r = 0; r < 8; ++r) {
                union { float4 f4; half8 h8; } cv;
                cv.f4 = raw[r];
                #pragma unroll
                for (int j = 0; j < 8; ++j)
                    acc[j] = fmaf((float)cv.h8[j], wg[r], acc[j]);
            }
        }
    }
    if (act) {
        float inv = 1.0f / fmaxf((float)cnt, 1.0f);
        union { __half2 h2[4]; short8 s8; } u;
        #pragma unroll
        for (int j = 0; j < 4; ++j)
            u.h2[j] = __floats2half2_rn(acc[2 * j] * inv, acc[2 * j + 1] * inv);
        *(short8*)(agg + (size_t)node * D + sub * 8) = u.s8;
    }
}

// ------------------------------------------------ fp16 2-term MFMA GEMM, LDS-staged B
// (R5 measured-good version: 512 thr = 8 waves = 256 rows per 16KB B-stage)
__global__ __launch_bounds__(512)
void mfma_gemm_k(const _Float16* __restrict__ A0, const _Float16* __restrict__ A1,
                 const unsigned short* __restrict__ Wg,
                 const float* __restrict__ bias,
                 float* __restrict__ C, __half* __restrict__ Ch,
                 int n, int out_mode) {
    __shared__ __align__(16) unsigned short lds_b[8192];   // 16 KB
    int t = threadIdx.x;
    int w = t >> 6;
    int l = t & 63;
    int m = l & 15;          // A row within tile / B,C col within tile
    int q = l >> 4;          // quad
    int r0 = blockIdx.x * 256 + w * 32;

    f32x4 acc[2][8];
    #pragma unroll
    for (int rt = 0; rt < 2; ++rt)
        #pragma unroll
        for (int ct = 0; ct < 8; ++ct)
            acc[rt][ct] = (f32x4){0.f, 0.f, 0.f, 0.f};

    for (int kc = 0; kc < 8; ++kc) {
        const unsigned short* gk = Wg + (size_t)kc * 8192;
        #pragma unroll
        for (int i = 0; i < 2; ++i) {
            int e = i * 512 + t;
            __builtin_amdgcn_global_load_lds(AS1(gk + e * 8), AS3(lds_b + e * 8), 16, 0, 0);
        }
        const _Float16* __restrict__ A = (kc < 4) ? A0 : A1;
        int ka = (kc & 3) * 32;
        half8 a[2];
        #pragma unroll
        for (int rt = 0; rt < 2; ++rt) {
            int row = r0 + rt * 16 + m;
            half8 v = (half8){0, 0, 0, 0, 0, 0, 0, 0};
            if (row < n) v = *(const half8*)(A + (size_t)row * D + ka + q * 8);
            a[rt] = v;
        }
        __syncthreads();

        #pragma unroll
        for (int ct = 0; ct < 8; ++ct) {
            half8 bh = *(const half8*)&lds_b[(size_t)(q * 128 + ct * 16 + m) * 8];
            half8 bl = *(const half8*)&lds_b[(size_t)((4 + q) * 128 + ct * 16 + m) * 8];
            #pragma unroll
            for (int rt = 0; rt < 2; ++rt) {
                acc[rt][ct] = __builtin_amdgcn_mfma_f32_16x16x32_f16(a[rt], bh, acc[rt][ct], 0, 0, 0);
                acc[rt][ct] = __builtin_amdgcn_mfma_f32_16x16x32_f16(a[rt], bl, acc[rt][ct], 0, 0, 0);
            }
        }
        __syncthreads();
    }

    #pragma unroll
    for (int ct = 0; ct < 8; ++ct) {
        int col = ct * 16 + m;
        float bb = bias[col];
        #pragma unroll
        for (int rt = 0; rt < 2; ++rt) {
            #pragma unroll
            for (int r = 0; r < 4; ++r) {
                int row = r0 + rt * 16 + q * 4 + r;
                if (row < n) {
                    float v = acc[rt][ct][r] + bb;
                    if (out_mode) {
                        v = fmaxf(v, 0.f);
                        Ch[(size_t)row * D + col] = __float2half(v);
                    } else {
                        C[(size_t)row * D + col] = v;
                    }
                }
            }
        }
    }
}

// ------------------------------------------------------------------- launch
extern "C" void kernel_launch(void* const* d_in, const int* in_sizes, int n_in,
                              void* d_out, int out_size, void* d_ws, size_t ws_size,
                              hipStream_t stream) {
    const float* in_feat = (const float*)d_in[0];
    const float* W1s     = (const float*)d_in[1];
    const float* W1n     = (const float*)d_in[2];
    const float* b1      = (const float*)d_in[3];
    const float* W2s     = (const float*)d_in[4];
    const float* W2n     = (const float*)d_in[5];
    const float* b2      = (const float*)d_in[6];
    const int*   src     = (const int*)d_in[7];
    const int*   dst     = (const int*)d_in[8];

    const int N  = in_sizes[0] / D;
    const int E  = in_sizes[7];
    const int NB = (N + 255) >> 8;     // 256-node buckets

    // workspace layout
    char* base = (char*)d_ws;
    size_t off = 0;
    __half* agg16 = (__half*)(base + off); off += (size_t)N * D * 2;   // neighbor means
    __half* xh16  = (__half*)(base + off); off += (size_t)N * D * 2;   // x16, then h16 (in-place)
    int* edge_src = (int*)(base + off);    off += (size_t)E * 4;
    int* counts   = (int*)(base + off);    off += (size_t)N * 4;
    int* offsets  = (int*)(base + off);    off += (size_t)N * 4;
    unsigned short* Wg1 = (unsigned short*)(base + off); off += 65536 * 2;
    unsigned short* Wg2 = (unsigned short*)(base + off); off += 65536 * 2;
    int* bucket_counts = (int*)(base + off); off += NB_MAX * 4;
    int* bucket_base   = (int*)(base + off); off += (NB_MAX + 1) * 4;
    off = (off + 15) & ~(size_t)15;
    int* bucket_cursor = (int*)(base + off); off += NB_MAX * 4;

    unsigned* pairs = (unsigned*)agg16;  // aliases agg16 (consumed before agg16 written)

    const int chunk = (E + PART_BLOCKS - 1) / PART_BLOCKS;
    const int n4 = (N * D) / 4;
    const int xb = (n4 + 255) / 256;
    const int zb = (NB + 255) / 256;

    // fused prep: x->fp16, W1/W2 hi-lo split, zero bucket counts
    hipLaunchKernelGGL(prep_k, dim3(xb + 512 + zb), dim3(256), 0, stream,
                       in_feat, xh16, n4, W1s, W1n, W2s, W2n, Wg1, Wg2,
                       bucket_counts, NB, xb);

    // CSR build (bucketed counting sort by dst)
    hipLaunchKernelGGL(bucket_count_k, dim3(PART_BLOCKS), dim3(256), 0, stream,
                       dst, bucket_counts, E, NB);
    hipLaunchKernelGGL(bucket_scan_k, dim3(1), dim3(256), 0, stream,
                       bucket_counts, bucket_base, bucket_cursor, NB);
    hipLaunchKernelGGL(partition_k, dim3(PART_BLOCKS), dim3(256), 0, stream,
                       src, dst, bucket_cursor, pairs, E, NB, chunk);
    hipLaunchKernelGGL(build_csr_k, dim3(NB), dim3(256), 0, stream,
                       pairs, bucket_base, counts, offsets, edge_src, N);

    const int nwaves = (N + 3) / 4;
    const dim3 aggGrid(((size_t)nwaves * 64 + 255) / 256);
    const dim3 gemmGrid((N + 255) / 256);

    // layer 1: agg(x16) -> gemm -> h16 (in-place into xh16)
    hipLaunchKernelGGL(aggregate_f16_k, aggGrid, dim3(256), 0, stream,
                       xh16, edge_src, offsets, counts, agg16, N);
    hipLaunchKernelGGL(mfma_gemm_k, gemmGrid, dim3(512), 0, stream,
                       (const _Float16*)xh16, (const _Float16*)agg16, Wg1, b1,
                       (float*)nullptr, xh16, N, 1);

    // layer 2: agg(h16) -> gemm -> d_out fp32
    hipLaunchKernelGGL(aggregate_f16_k, aggGrid, dim3(256), 0, stream,
                       xh16, edge_src, offsets, counts, agg16, N);
    hipLaunchKernelGGL(mfma_gemm_k, gemmGrid, dim3(512), 0, stream,
                       (const _Float16*)xh16, (const _Float16*)agg16, Wg2, b2,
                       (float*)d_out, (__half*)nullptr, N, 0);
}